// Round 1
// 1745.045 us; speedup vs baseline: 1.0073x; 1.0073x over previous
//
#include <hip/hip_runtime.h>

#define BB 8
#define NN 4096
#define KK 20
constexpr float EPSV = 1e-5f;
constexpr float SLOPE = 0.2f;

typedef __bf16 bfrag __attribute__((ext_vector_type(8)));
typedef float floatx4 __attribute__((ext_vector_type(4)));
typedef unsigned short us4 __attribute__((ext_vector_type(4)));

__device__ __forceinline__ float lrelu(float v) { return v >= 0.f ? v : SLOPE * v; }

__device__ __forceinline__ unsigned short bf16rn(float f) {
    unsigned int u = __float_as_uint(f);
    return (unsigned short)((u + 0x7FFFu + ((u >> 16) & 1u)) >> 16);
}
__device__ __forceinline__ float bf16up(unsigned short h) {
    return __uint_as_float(((unsigned int)h) << 16);
}

__global__ void zero_kernel(float* p, int n) {
    int i = blockIdx.x * 256 + threadIdx.x;
    if (i < n) p[i] = 0.f;
}

// 0.5*||x_n||^2 per point (exact fp32). grid (NN/256, BB), block 256.
template<int C>
__global__ void halfnorm_kernel(const float* __restrict__ src, float* __restrict__ hng) {
    int n = blockIdx.x * 256 + threadIdx.x;
    int b = blockIdx.y;
    float s = 0.f;
    #pragma unroll
    for (int c = 0; c < C; c++) { float v = src[(b * C + c) * NN + n]; s += v * v; }
    hng[b * NN + n] = 0.5f * s;
}

// ---------------- kNN via MFMA (bf16 hi/lo split, 4-term exact) ----------------
// Score s(q,m) = dot(q,m) - 0.5||x_m||^2 (same top-k set as reference).
// Block 256 (4 waves); tile 64q x 64m per chunk; wave owns 32x32 (4 MFMA acc tiles).
// NEW vs prev round:
//  * register double-buffer of candidate staging (prefetch ch+1 during ch) —
//    global-load latency no longer sits on the per-chunk critical path.
//  * 4-way parallel drain: thread tid owns q=tid&63, sublane=tid>>6 takes pool
//    entries t≡sublane (mod 4); each keeps a PARTIAL top-20. Filter threshold =
//    max of the 4 partial mins (<= true 20th-best, so never drops a true
//    neighbor). Exact top-20 rebuilt by a one-time 60-entry merge at the end.
template<int C>
__global__ __launch_bounds__(256) void knn_kernel(const float* __restrict__ src,
                                                  const float* __restrict__ hng,
                                                  int* __restrict__ idx) {
    constexpr int SK = (C == 3) ? 40 : (2 * C + 8);   // padded k-stride (shorts)
    constexpr int PFN = (C == 3) ? 3 : (C / 4);       // prefetch regs per thread
    __shared__ unsigned short qpack[64 * SK];
    __shared__ unsigned short cpack[64 * SK];
    __shared__ float hn[64];
    __shared__ float pv[64 * 65];
    __shared__ unsigned short pidx[64 * 66];
    __shared__ float tau[256];                        // [sublane][q]
    __shared__ int   cnt[64];

    const int b = blockIdx.y;
    const int q0 = blockIdx.x * 64;
    const int tid = threadIdx.x;
    const int lane = tid & 63;
    const int wv = tid >> 6;
    const int wr = (wv >> 1) * 32;      // wave q-offset in [0,64)
    const int wc = (wv & 1) * 32;       // wave m-offset in [0,64)
    const int fl = lane & 15;
    const int fq = lane >> 4;
    const int dq = tid & 63;            // drain: q owned by this thread
    const int ds = tid >> 6;            // drain: sublane (pool partition)

    float pf[PFN];                      // prefetched candidate floats
    float4 hnp;                         // prefetched half-norms (tid<16)

    // ---- stage queries (hi/lo bf16) ----
    if (C == 3) {
        // zero pad region k in [12,32) for both qpack and cpack rows
        for (int i = tid; i < 64 * 20; i += 256) {
            int r = i / 20, k = 12 + i % 20;
            qpack[r * SK + k] = 0; cpack[r * SK + k] = 0;
        }
        if (tid < 64) {
            int q = tid;
            #pragma unroll
            for (int c = 0; c < 3; c++) {
                float v = src[(b * 3 + c) * NN + q0 + q];
                unsigned short h = bf16rn(v);
                unsigned short l = bf16rn(v - bf16up(h));
                // A-pack: [qh(3) | ql(3) | qh(3) | ql(3) | 0...]
                qpack[q * SK + c] = h;  qpack[q * SK + 3 + c] = l;
                qpack[q * SK + 6 + c] = h;  qpack[q * SK + 9 + c] = l;
            }
        }
    } else {
        for (int t = 0; t < C / 16; t++) {
            int i = t * 256 + tid;
            int c4 = (i >> 6) * 4, m = i & 63;
            us4 hv, lv;
            #pragma unroll
            for (int j = 0; j < 4; j++) {
                float v = src[(b * C + c4 + j) * NN + q0 + m];
                unsigned short h = bf16rn(v);
                hv[j] = h;
                lv[j] = bf16rn(v - bf16up(h));
            }
            *(us4*)(&qpack[m * SK + c4]) = hv;          // qh region [0,C)
            *(us4*)(&qpack[m * SK + C + c4]) = lv;      // ql region [C,2C)
        }
    }
    tau[tid] = -3.4e38f;

    float tv[20]; int ti[20];
    #pragma unroll
    for (int k = 0; k < 20; k++) { tv[k] = -3.4e38f; ti[k] = 0; }

    // ---- prefetch chunk 0 into registers ----
    if (C == 3) {
        if (tid < 64) {
            #pragma unroll
            for (int c = 0; c < 3; c++) pf[c] = src[(b * 3 + c) * NN + tid];
        }
    } else {
        #pragma unroll
        for (int t = 0; t < C / 16; t++) {
            int i = t * 256 + tid;
            int c4 = (i >> 6) * 4, m = i & 63;
            #pragma unroll
            for (int j = 0; j < 4; j++)
                pf[t * 4 + j] = src[(b * C + c4 + j) * NN + m];
        }
    }
    if (tid < 16) hnp = *(const float4*)(hng + b * NN + tid * 4);

    for (int ch = 0; ch < 64; ch++) {
        const int m0 = ch * 64;
        // ---- phase S: commit prefetched chunk to LDS ----
        if (C == 3) {
            if (tid < 64) {
                int m = tid;
                #pragma unroll
                for (int c = 0; c < 3; c++) {
                    float v = pf[c];
                    unsigned short h = bf16rn(v);
                    unsigned short l = bf16rn(v - bf16up(h));
                    // B-pack: [ch(3) | cl(3) | cl(3) | ch(3) | 0...] -> hh+ll+hl+lh
                    cpack[m * SK + c] = h;  cpack[m * SK + 3 + c] = l;
                    cpack[m * SK + 6 + c] = l;  cpack[m * SK + 9 + c] = h;
                }
            }
        } else {
            #pragma unroll
            for (int t = 0; t < C / 16; t++) {
                int i = t * 256 + tid;
                int c4 = (i >> 6) * 4, m = i & 63;
                us4 hv, lv;
                #pragma unroll
                for (int j = 0; j < 4; j++) {
                    float v = pf[t * 4 + j];
                    unsigned short h = bf16rn(v);
                    hv[j] = h;
                    lv[j] = bf16rn(v - bf16up(h));
                }
                *(us4*)(&cpack[m * SK + c4]) = hv;
                *(us4*)(&cpack[m * SK + C + c4]) = lv;
            }
        }
        if (tid < 16) *(float4*)(hn + tid * 4) = hnp;
        if (tid < 64) cnt[tid] = 0;

        // ---- issue prefetch for ch+1 (latency hides under MFMA+filter+drain) ----
        if (ch + 1 < 64) {
            const int m1 = m0 + 64;
            if (C == 3) {
                if (tid < 64) {
                    #pragma unroll
                    for (int c = 0; c < 3; c++) pf[c] = src[(b * 3 + c) * NN + m1 + tid];
                }
            } else {
                #pragma unroll
                for (int t = 0; t < C / 16; t++) {
                    int i = t * 256 + tid;
                    int c4 = (i >> 6) * 4, m = i & 63;
                    #pragma unroll
                    for (int j = 0; j < 4; j++)
                        pf[t * 4 + j] = src[(b * C + c4 + j) * NN + m1 + m];
                }
            }
            if (tid < 16) hnp = *(const float4*)(hng + b * NN + m1 + tid * 4);
        }
        __syncthreads();

        // ---- MFMA: acc[r2][c2] = 32x32 wave tile scores ----
        floatx4 acc[2][2];
        #pragma unroll
        for (int r2 = 0; r2 < 2; r2++)
            #pragma unroll
            for (int c2 = 0; c2 < 2; c2++)
                acc[r2][c2] = (floatx4)(0.f);

        if (C == 3) {
            #pragma unroll
            for (int r2 = 0; r2 < 2; r2++) {
                bfrag a = *(const bfrag*)(&qpack[(wr + r2 * 16 + fl) * SK + fq * 8]);
                #pragma unroll
                for (int c2 = 0; c2 < 2; c2++) {
                    bfrag bm = *(const bfrag*)(&cpack[(wc + c2 * 16 + fl) * SK + fq * 8]);
                    acc[r2][c2] = __builtin_amdgcn_mfma_f32_16x16x32_bf16(a, bm, acc[r2][c2], 0, 0, 0);
                }
            }
        } else {
            #pragma unroll
            for (int kk = 0; kk < C / 32; kk++) {
                const int kb = kk * 32 + fq * 8;
                bfrag ah[2], al[2], bh[2], bl[2];
                #pragma unroll
                for (int r2 = 0; r2 < 2; r2++) {
                    ah[r2] = *(const bfrag*)(&qpack[(wr + r2 * 16 + fl) * SK + kb]);
                    al[r2] = *(const bfrag*)(&qpack[(wr + r2 * 16 + fl) * SK + C + kb]);
                }
                #pragma unroll
                for (int c2 = 0; c2 < 2; c2++) {
                    bh[c2] = *(const bfrag*)(&cpack[(wc + c2 * 16 + fl) * SK + kb]);
                    bl[c2] = *(const bfrag*)(&cpack[(wc + c2 * 16 + fl) * SK + C + kb]);
                }
                #pragma unroll
                for (int r2 = 0; r2 < 2; r2++)
                    #pragma unroll
                    for (int c2 = 0; c2 < 2; c2++) {
                        acc[r2][c2] = __builtin_amdgcn_mfma_f32_16x16x32_bf16(ah[r2], bh[c2], acc[r2][c2], 0, 0, 0);
                        acc[r2][c2] = __builtin_amdgcn_mfma_f32_16x16x32_bf16(ah[r2], bl[c2], acc[r2][c2], 0, 0, 0);
                        acc[r2][c2] = __builtin_amdgcn_mfma_f32_16x16x32_bf16(al[r2], bh[c2], acc[r2][c2], 0, 0, 0);
                        acc[r2][c2] = __builtin_amdgcn_mfma_f32_16x16x32_bf16(al[r2], bl[c2], acc[r2][c2], 0, 0, 0);
                    }
            }
        }

        // ---- filter: C-layout col=lane&15, row=fq*4+reg; threshold = max of 4 partial taus ----
        float hnv[2];
        #pragma unroll
        for (int c2 = 0; c2 < 2; c2++) hnv[c2] = hn[wc + c2 * 16 + fl];
        #pragma unroll
        for (int r2 = 0; r2 < 2; r2++) {
            const int qq = wr + r2 * 16 + fq * 4;
            float4 t0 = *(const float4*)(&tau[qq]);
            float4 t1 = *(const float4*)(&tau[64 + qq]);
            float4 t2 = *(const float4*)(&tau[128 + qq]);
            float4 t3 = *(const float4*)(&tau[192 + qq]);
            float ta[4] = { fmaxf(fmaxf(t0.x, t1.x), fmaxf(t2.x, t3.x)),
                            fmaxf(fmaxf(t0.y, t1.y), fmaxf(t2.y, t3.y)),
                            fmaxf(fmaxf(t0.z, t1.z), fmaxf(t2.z, t3.z)),
                            fmaxf(fmaxf(t0.w, t1.w), fmaxf(t2.w, t3.w)) };
            #pragma unroll
            for (int c2 = 0; c2 < 2; c2++) {
                #pragma unroll
                for (int reg = 0; reg < 4; reg++) {
                    float s = acc[r2][c2][reg] - hnv[c2];
                    if (s > ta[reg]) {
                        int q = qq + reg;
                        int p = atomicAdd(&cnt[q], 1);     // <= 64 per chunk: fits
                        pv[q * 65 + p] = s;
                        pidx[q * 66 + p] = (unsigned short)(m0 + wc + c2 * 16 + fl);
                    }
                }
            }
        }
        __syncthreads();

        // ---- parallel drain: 4 sublanes per q, each keeps a partial top-20 ----
        {
            int n = cnt[dq];
            for (int t = ds; t < n; t += 4) {
                float v = pv[dq * 65 + t];
                if (v > tv[0]) {
                    tv[0] = v; ti[0] = (int)pidx[dq * 66 + t];
                    #pragma unroll
                    for (int j = 0; j < 19; j++) {
                        if (tv[j] > tv[j + 1]) {
                            float a = tv[j]; tv[j] = tv[j + 1]; tv[j + 1] = a;
                            int bi = ti[j]; ti[j] = ti[j + 1]; ti[j + 1] = bi;
                        }
                    }
                }
            }
            tau[tid] = tv[0];
        }
        __syncthreads();
    }

    // ---- merge the 4 partial top-20s into the exact top-20 (once) ----
    if (ds > 0) {
        #pragma unroll
        for (int k = 0; k < 20; k++) {
            pv[dq * 65 + (ds - 1) * 20 + k] = tv[k];
            pidx[dq * 66 + (ds - 1) * 20 + k] = (unsigned short)ti[k];
        }
    }
    __syncthreads();
    if (tid < 64) {
        for (int t = 0; t < 60; t++) {
            float v = pv[tid * 65 + t];
            if (v > tv[0]) {
                tv[0] = v; ti[0] = (int)pidx[tid * 66 + t];
                #pragma unroll
                for (int j = 0; j < 19; j++) {
                    if (tv[j] > tv[j + 1]) {
                        float a = tv[j]; tv[j] = tv[j + 1]; tv[j + 1] = a;
                        int bi = ti[j]; ti[j] = ti[j + 1]; ti[j + 1] = bi;
                    }
                }
            }
        }
        #pragma unroll
        for (int k = 0; k < 20; k++)
            idx[(b * NN + q0 + tid) * KK + k] = ti[k];   // order irrelevant downstream
    }
}

// ---------------- conv precompute: G = Wd*src, H = (Wc-Wd)*src ----------------
template<int COUT>
__global__ void precompute_kernel(const float* __restrict__ src, int C,
                                  const float* __restrict__ w, int CIN, int wd_off, int wc_off,
                                  float* __restrict__ G, float* __restrict__ H,
                                  int initG, int initH) {
    constexpr int MY = 256 / COUT;
    extern __shared__ float lds[];
    float* wd = lds;
    float* wc = lds + C * COUT;
    const int b = blockIdx.y;
    const int tid = threadIdx.y * COUT + threadIdx.x;
    for (int i = tid; i < C * COUT; i += 256) {
        int c = i / COUT, o = i % COUT;
        float a  = w[o * CIN + wd_off + c];
        float cc = w[o * CIN + wc_off + c];
        wd[i] = a;
        wc[i] = cc - a;
    }
    __syncthreads();
    const int o = threadIdx.x;
    for (int it = 0; it < COUT / 4; it++) {
        int m = blockIdx.x * 64 + it * MY + threadIdx.y;
        float g = 0.f, h = 0.f;
        for (int c = 0; c < C; c++) {
            float s = src[(b * C + c) * NN + m];
            g += wd[c * COUT + o] * s;
            h += wc[c * COUT + o] * s;
        }
        int gi = (b * NN + m) * COUT + o;
        if (initG) G[gi] = g; else G[gi] += g;
        if (initH) H[gi] = h; else H[gi] += h;
    }
}

// ---------------- conv stats + per-(b,n,o) min/max over k ----------------
template<int COUT, int GROUPS>
__global__ void conv_stats_kernel(const float* __restrict__ G1, const int* __restrict__ idx1,
                                  const float* __restrict__ G2, const int* __restrict__ idx2,
                                  const float* __restrict__ H, float* __restrict__ stats,
                                  float* __restrict__ MaxY, float* __restrict__ MinY) {
    constexpr int NY = 256 / COUT;
    const int b = blockIdx.y;
    const int o = threadIdx.x;
    const int n = blockIdx.x * NY + threadIdx.y;
    const int base = b * NN + n;
    const float h = H[base * COUT + o];
    float s1 = 0.f, s2 = 0.f;
    float gx = -3.4e38f, gn = 3.4e38f;
    #pragma unroll
    for (int k = 0; k < KK; k++) {
        int i1 = idx1[base * KK + k];
        float g = G1[(b * NN + i1) * COUT + o];
        if (GROUPS == 2) {
            int i2 = idx2[base * KK + k];
            g += G2[(b * NN + i2) * COUT + o];
        }
        float y = g + h;
        s1 += y;
        s2 += y * y;
        gx = fmaxf(gx, g);
        gn = fminf(gn, g);
    }
    MaxY[base * COUT + o] = gx + h;
    MinY[base * COUT + o] = gn + h;

    __shared__ float ls[2 * COUT];
    if (threadIdx.y == 0) { ls[o] = 0.f; ls[COUT + o] = 0.f; }
    __syncthreads();
    atomicAdd(&ls[o], s1);
    atomicAdd(&ls[COUT + o], s2);
    __syncthreads();
    if (threadIdx.y == 0) {
        atomicAdd(&stats[o], ls[o]);
        atomicAdd(&stats[64 + o], ls[COUT + o]);
    }
}

__global__ void finalize_kernel(const float* __restrict__ g, const float* __restrict__ bb,
                                float* __restrict__ stats, int cout, float invP) {
    int o = threadIdx.x;
    if (o >= cout) return;
    float mu  = stats[o] * invP;
    float var = stats[64 + o] * invP - mu * mu;
    float sc  = g[o] * rsqrtf(var + EPSV);
    stats[128 + o] = sc;
    stats[192 + o] = bb[o] - mu * sc;
}

__global__ void apply_kernel(const float* __restrict__ MaxY, const float* __restrict__ MinY,
                             const float* __restrict__ stats, float* __restrict__ out, int cout) {
    int e = blockIdx.x * 256 + threadIdx.x;
    int total = BB * cout * NN;
    if (e >= total) return;
    int n = e & (NN - 1);
    int o = (e >> 12) % cout;
    int b = e / (NN * cout);
    float sc = stats[128 + o], sh = stats[192 + o];
    int si = (b * NN + n) * cout + o;
    float v = (sc >= 0.f) ? MaxY[si] : MinY[si];
    out[e] = lrelu(sc * v + sh);
}

__global__ void mean_kernel(const float* __restrict__ xd1, const float* __restrict__ xd2,
                            float* __restrict__ hsum) {
    __shared__ float bins[128];
    const int tid = threadIdx.x;
    if (tid < 128) bins[tid] = 0.f;
    __syncthreads();
    const int half = BB * 64 * NN;
    const int stride = gridDim.x * 256;
    for (int e = blockIdx.x * 256 + tid; e < half; e += stride)
        atomicAdd(&bins[e & 127], xd1[e]);
    for (int e = blockIdx.x * 256 + tid; e < half; e += stride)
        atomicAdd(&bins[e & 127], xd2[e]);
    __syncthreads();
    if (tid < 128) atomicAdd(&hsum[tid], bins[tid]);
}

__global__ void head_kernel(const float* __restrict__ hsum,
                            const float* __restrict__ W2d, const float* __restrict__ b2d,
                            const float* __restrict__ W3d, const float* __restrict__ b3d,
                            const float* __restrict__ W4d, const float* __restrict__ b4d,
                            float* __restrict__ out) {
    __shared__ float h[128], t1[128], t2[64];
    const int t = threadIdx.x;
    h[t] = hsum[t] * (1.f / 32768.f);
    __syncthreads();
    float a = b2d[t];
    for (int j = 0; j < 128; j++) a += W2d[t * 128 + j] * h[j];
    t1[t] = lrelu(a);
    __syncthreads();
    if (t < 64) {
        float a2 = b3d[t];
        for (int j = 0; j < 128; j++) a2 += W3d[t * 128 + j] * t1[j];
        t2[t] = lrelu(a2);
    }
    __syncthreads();
    if (t < 11) {
        float a3 = b4d[t];
        for (int j = 0; j < 64; j++) a3 += W4d[t * 64 + j] * t2[j];
        out[t] = lrelu(a3);
    }
}

extern "C" void kernel_launch(void* const* d_in, const int* in_sizes, int n_in,
                              void* d_out, int out_size, void* d_ws, size_t ws_size,
                              hipStream_t stream) {
    const float* x   = (const float*)d_in[0];
    const float* w1  = (const float*)d_in[1];
    const float* g1  = (const float*)d_in[2];
    const float* b1  = (const float*)d_in[3];
    const float* w2  = (const float*)d_in[4];
    const float* g2  = (const float*)d_in[5];
    const float* b2  = (const float*)d_in[6];
    const float* wd1 = (const float*)d_in[7];
    const float* gd1 = (const float*)d_in[8];
    const float* bd1 = (const float*)d_in[9];
    const float* wd2 = (const float*)d_in[10];
    const float* gd2 = (const float*)d_in[11];
    const float* bd2 = (const float*)d_in[12];
    const float* W2d = (const float*)d_in[13];
    const float* b2d = (const float*)d_in[14];
    const float* W3d = (const float*)d_in[15];
    const float* b3d = (const float*)d_in[16];
    const float* W4d = (const float*)d_in[17];
    const float* b4d = (const float*)d_in[18];
    float* out = (float*)d_out;

    char* ws = (char*)d_ws;
    size_t off = 0;
    auto alloc = [&](size_t bytes) { char* p = ws + off; off += (bytes + 255) & ~size_t(255); return p; };
    int*   idx1  = (int*)  alloc(BB * NN * KK * 4);
    int*   idx2  = (int*)  alloc(BB * NN * KK * 4);
    int*   idx3  = (int*)  alloc(BB * NN * KK * 4);
    float* x1m   = (float*)alloc(BB * 32 * NN * 4);
    float* x2m   = (float*)alloc(BB * 64 * NN * 4);
    float* xd1   = (float*)alloc(BB * 64 * NN * 4);
    float* xd2   = (float*)alloc(BB * 64 * NN * 4);
    float* G1    = (float*)alloc((size_t)BB * NN * 64 * 4);
    float* G2    = (float*)alloc((size_t)BB * NN * 64 * 4);
    float* H     = (float*)alloc((size_t)BB * NN * 64 * 4);
    float* MaxY  = (float*)alloc((size_t)BB * NN * 64 * 4);
    float* MinY  = (float*)alloc((size_t)BB * NN * 64 * 4);
    float* stats = (float*)alloc(256 * 4);
    float* hsum  = (float*)alloc(128 * 4);
    float* hng   = (float*)alloc(BB * NN * 4);

    const float invP = 1.f / (float)(BB * NN * KK);
    const dim3 knn_grid(NN / 64, BB);
    const dim3 hn_grid(NN / 256, BB);

    zero_kernel<<<1, 256, 0, stream>>>(hsum, 128);

    // --- kNN on x (C=3) ---
    halfnorm_kernel<3><<<hn_grid, 256, 0, stream>>>(x, hng);
    knn_kernel<3><<<knn_grid, 256, 0, stream>>>(x, hng, idx1);

    // --- conv1: Cout=32, group (x, idx1, C=3), w1 CIN=6 ---
    zero_kernel<<<1, 256, 0, stream>>>(stats, 128);
    precompute_kernel<32><<<dim3(NN / 64, BB), dim3(32, 8), 2 * 3 * 32 * 4, stream>>>(
        x, 3, w1, 6, 0, 3, G1, H, 1, 1);
    conv_stats_kernel<32, 1><<<dim3(NN / 8, BB), dim3(32, 8), 0, stream>>>(
        G1, idx1, nullptr, nullptr, H, stats, MaxY, MinY);
    finalize_kernel<<<1, 64, 0, stream>>>(g1, b1, stats, 32, invP);
    apply_kernel<<<(BB * 32 * NN + 255) / 256, 256, 0, stream>>>(MaxY, MinY, stats, x1m, 32);

    // --- kNN on x1_max (C=32) ---
    halfnorm_kernel<32><<<hn_grid, 256, 0, stream>>>(x1m, hng);
    knn_kernel<32><<<knn_grid, 256, 0, stream>>>(x1m, hng, idx2);

    // --- conv2: Cout=64, groups (x, idx1, 3) + (x1m, idx2, 32), w2 CIN=70 ---
    zero_kernel<<<1, 256, 0, stream>>>(stats, 128);
    precompute_kernel<64><<<dim3(NN / 64, BB), dim3(64, 4), 2 * 3 * 64 * 4, stream>>>(
        x, 3, w2, 70, 0, 3, G1, H, 1, 1);
    precompute_kernel<64><<<dim3(NN / 64, BB), dim3(64, 4), 2 * 32 * 64 * 4, stream>>>(
        x1m, 32, w2, 70, 6, 38, G2, H, 1, 0);
    conv_stats_kernel<64, 2><<<dim3(NN / 4, BB), dim3(64, 4), 0, stream>>>(
        G1, idx1, G2, idx2, H, stats, MaxY, MinY);
    finalize_kernel<<<1, 64, 0, stream>>>(g2, b2, stats, 64, invP);
    apply_kernel<<<(BB * 64 * NN + 255) / 256, 256, 0, stream>>>(MaxY, MinY, stats, x2m, 64);

    // --- convd1: Cout=64, group (x1m, idx2, 32), wd1 CIN=64 ---
    zero_kernel<<<1, 256, 0, stream>>>(stats, 128);
    precompute_kernel<64><<<dim3(NN / 64, BB), dim3(64, 4), 2 * 32 * 64 * 4, stream>>>(
        x1m, 32, wd1, 64, 0, 32, G1, H, 1, 1);
    conv_stats_kernel<64, 1><<<dim3(NN / 4, BB), dim3(64, 4), 0, stream>>>(
        G1, idx2, nullptr, nullptr, H, stats, MaxY, MinY);
    finalize_kernel<<<1, 64, 0, stream>>>(gd1, bd1, stats, 64, invP);
    apply_kernel<<<(BB * 64 * NN + 255) / 256, 256, 0, stream>>>(MaxY, MinY, stats, xd1, 64);

    // --- kNN on x2_max (C=64) ---
    halfnorm_kernel<64><<<hn_grid, 256, 0, stream>>>(x2m, hng);
    knn_kernel<64><<<knn_grid, 256, 0, stream>>>(x2m, hng, idx3);

    // --- convd2: Cout=64, group (x2m, idx3, 64), wd2 CIN=128 ---
    zero_kernel<<<1, 256, 0, stream>>>(stats, 128);
    precompute_kernel<64><<<dim3(NN / 64, BB), dim3(64, 4), 2 * 64 * 64 * 4, stream>>>(
        x2m, 64, wd2, 128, 0, 64, G1, H, 1, 1);
    conv_stats_kernel<64, 1><<<dim3(NN / 4, BB), dim3(64, 4), 0, stream>>>(
        G1, idx3, nullptr, nullptr, H, stats, MaxY, MinY);
    finalize_kernel<<<1, 64, 0, stream>>>(gd2, bd2, stats, 64, invP);
    apply_kernel<<<(BB * 64 * NN + 255) / 256, 256, 0, stream>>>(MaxY, MinY, stats, xd2, 64);

    // --- global mean + MLP head ---
    mean_kernel<<<1024, 256, 0, stream>>>(xd1, xd2, hsum);
    head_kernel<<<1, 128, 0, stream>>>(hsum, W2d, b2d, W3d, b3d, W4d, b4d, out);
}